// Round 1
// baseline (3952.081 us; speedup 1.0000x reference)
//
#include <hip/hip_runtime.h>
#include <cstdint>
#include <cstddef>

#define NB 4
#define NN 8192
#define NPTS 2048
#define NSAMP 32
#define NC 128
#define CIN 131      // 3 + NC
#define NH1 64
#define NH2 128
#define NOUTC 128

// Exact (numpy-order, contraction-free) squared distance:
// ((dx*dx + dy*dy) + dz*dz), round-to-nearest each op, no FMA.
__device__ __forceinline__ float d2_exact(float ax, float ay, float az,
                                          float bx, float by, float bz) {
  float dx = ax - bx, dy = ay - by, dz = az - bz;
  return __fadd_rn(__fadd_rn(__fmul_rn(dx, dx), __fmul_rn(dy, dy)),
                   __fmul_rn(dz, dz));
}

// ---------------------------------------------------------------------------
// FPS: one 1024-thread block per batch; 8 points per thread held in regs.
// Bit-exact vs reference: dist=min(dist,d) then argmax(dist), first-index ties.
// ---------------------------------------------------------------------------
__global__ __launch_bounds__(1024, 1) void fps_kernel(
    const float* __restrict__ xyz, float* __restrict__ newxyz) {
  const int b = blockIdx.x;
  const int tid = threadIdx.x;
  const float* xb = xyz + (size_t)b * NN * 3;
  float x[8], y[8], z[8], dist[8];
#pragma unroll
  for (int k = 0; k < 8; ++k) {
    int j = tid + (k << 10);
    x[k] = xb[j * 3 + 0];
    y[k] = xb[j * 3 + 1];
    z[k] = xb[j * 3 + 2];
    dist[k] = 1e10f;
  }
  __shared__ float sP[3];
  __shared__ float wv[16];
  __shared__ int wi[16];
  if (tid == 0) {
    sP[0] = x[0]; sP[1] = y[0]; sP[2] = z[0];
    newxyz[(size_t)b * NPTS * 3 + 0] = x[0];
    newxyz[(size_t)b * NPTS * 3 + 1] = y[0];
    newxyz[(size_t)b * NPTS * 3 + 2] = z[0];
  }
  __syncthreads();
  const int lane = tid & 63;
  const int wid = tid >> 6;
  for (int t = 1; t < NPTS; ++t) {
    float px = sP[0], py = sP[1], pz = sP[2];
    float bv = -1.0f;
    int bi = 0;
#pragma unroll
    for (int k = 0; k < 8; ++k) {
      float d = d2_exact(x[k], y[k], z[k], px, py, pz);
      float nd = fminf(dist[k], d);
      dist[k] = nd;
      if (nd > bv) { bv = nd; bi = tid + (k << 10); }  // ascending idx => first-max kept
    }
    // wave argmax (value desc, index asc on ties)
#pragma unroll
    for (int off = 1; off < 64; off <<= 1) {
      float ov = __shfl_xor(bv, off);
      int oi = __shfl_xor(bi, off);
      if (ov > bv || (ov == bv && oi < bi)) { bv = ov; bi = oi; }
    }
    if (lane == 0) { wv[wid] = bv; wi[wid] = bi; }
    __syncthreads();
    // all waves redundantly reduce the 16 partials (avoids a 3rd barrier)
    float v2 = (lane < 16) ? wv[lane] : -1.0f;
    int i2 = (lane < 16) ? wi[lane] : 0x7fffffff;
#pragma unroll
    for (int off = 1; off < 16; off <<= 1) {
      float ov = __shfl_xor(v2, off);
      int oi = __shfl_xor(i2, off);
      if (ov > v2 || (ov == v2 && oi < i2)) { v2 = ov; i2 = oi; }
    }
    int sel = __shfl(i2, 0);
    if (tid == (sel & 1023)) {  // owner broadcasts coords (bitwise the loaded xyz)
      int k = sel >> 10;
      sP[0] = x[k]; sP[1] = y[k]; sP[2] = z[k];
      size_t o = ((size_t)b * NPTS + t) * 3;
      newxyz[o + 0] = x[k]; newxyz[o + 1] = y[k]; newxyz[o + 2] = z[k];
    }
    __syncthreads();
  }
}

// ---------------------------------------------------------------------------
// Ball query: one wave per center; ballot scan in index order -> first 32 hits.
// 0.04f is bitwise the f32 rounding of python 0.2*0.2.
// ---------------------------------------------------------------------------
__global__ __launch_bounds__(256) void ballq_kernel(
    const float* __restrict__ xyz, const float* __restrict__ newxyz,
    int* __restrict__ bidx) {
  const int cid = blockIdx.x * 4 + (threadIdx.x >> 6);
  const int lane = threadIdx.x & 63;
  const int b = cid >> 11;
  const float* xb = xyz + (size_t)b * NN * 3;
  const float cx = newxyz[(size_t)cid * 3 + 0];
  const float cy = newxyz[(size_t)cid * 3 + 1];
  const float cz = newxyz[(size_t)cid * 3 + 2];
  int* ob = bidx + (size_t)cid * NSAMP;
  int total = 0;
  int first = -1;
  for (int c0 = 0; c0 < NN; c0 += 64) {
    int j = c0 + lane;
    float xx = xb[j * 3 + 0], yy = xb[j * 3 + 1], zz = xb[j * 3 + 2];
    float d2 = d2_exact(cx, cy, cz, xx, yy, zz);
    bool in = d2 <= 0.04f;
    unsigned long long m = __ballot(in);
    if (first < 0 && m) first = c0 + __builtin_ctzll(m);
    int pos = total + __popcll(m & ((1ull << lane) - 1ull));
    if (in && pos < NSAMP) ob[pos] = j;
    total += __popcll(m);
    if (total >= NSAMP) break;
  }
  if (total < NSAMP && lane < NSAMP - total) ob[total + lane] = first;
}

// ---------------------------------------------------------------------------
// Weight transposes (tiny) so MLP weight reads are lane-coalesced [k][o].
// ---------------------------------------------------------------------------
__global__ void tw_kernel(const float* __restrict__ W1, const float* __restrict__ W2,
                          const float* __restrict__ Wsa, float* __restrict__ w1t,
                          float* __restrict__ w2t, float* __restrict__ wsat) {
  int i = blockIdx.x * blockDim.x + threadIdx.x;
  if (i < CIN * NH1) w1t[i] = W1[(i % NH1) * CIN + (i / NH1)];
  if (i < NH1 * NH2) w2t[i] = W2[(i % NH2) * NH1 + (i / NH2)];
  if (i < NH2 * NOUTC) wsat[i] = Wsa[(i % NOUTC) * NH2 + (i / NOUTC)];
}

// Features (B,C,N) -> (B,N,C) so per-point gathers are contiguous 512B rows.
__global__ void tfeat_kernel(const float* __restrict__ feat, float* __restrict__ featT) {
  __shared__ float tile[32][33];
  const int b = blockIdx.z;
  const int n0 = blockIdx.x * 32, c0 = blockIdx.y * 32;
  const int tx = threadIdx.x, ty = threadIdx.y;
#pragma unroll
  for (int r = 0; r < 4; ++r)
    tile[ty + r * 8][tx] = feat[((size_t)b * NC + c0 + ty + r * 8) * NN + n0 + tx];
  __syncthreads();
#pragma unroll
  for (int r = 0; r < 4; ++r)
    featT[((size_t)b * NN + n0 + ty + r * 8) * NC + c0 + tx] = tile[tx][ty + r * 8];
}

// ---------------------------------------------------------------------------
// Fused gather + MLP(64,128) + maxpool + final linear, one block per center.
// LDS layouts [k][s] with stride 36 so operand reads are float4 broadcasts.
// ---------------------------------------------------------------------------
#define HS 36
__global__ __launch_bounds__(256) void mlp_kernel(
    const float* __restrict__ xyz, const float* __restrict__ fsrc,
    const float* __restrict__ newxyz, const int* __restrict__ bidx,
    const float* __restrict__ w1t, const float* __restrict__ b1,
    const float* __restrict__ w2t, const float* __restrict__ b2,
    const float* __restrict__ wsat, const float* __restrict__ bsa,
    float* __restrict__ out1, int useT) {
  __shared__ float h[CIN * HS];
  __shared__ float h1[NH1 * HS];
  __shared__ float pl[256];
  __shared__ float pooled[NH2];
  __shared__ int sidx[NSAMP];
  __shared__ float sc[3];
  const int cid = blockIdx.x;
  const int b = cid >> 11;
  const int s = cid & 2047;
  const int tid = threadIdx.x;
  if (tid < NSAMP) sidx[tid] = bidx[(size_t)cid * NSAMP + tid];
  if (tid < 3) sc[tid] = newxyz[(size_t)cid * 3 + tid];
  __syncthreads();
  {  // gather: 8 threads per sample read its 128-float feature row
    const int ss = tid >> 3, q = tid & 7;
    const int j = sidx[ss];
    if (useT) {
      const float4* fr = (const float4*)(fsrc + ((size_t)b * NN + j) * NC + q * 16);
#pragma unroll
      for (int u = 0; u < 4; ++u) {
        float4 v = fr[u];
        int c = 3 + q * 16 + u * 4;
        h[(c + 0) * HS + ss] = v.x;
        h[(c + 1) * HS + ss] = v.y;
        h[(c + 2) * HS + ss] = v.z;
        h[(c + 3) * HS + ss] = v.w;
      }
    } else {  // ws too small: strided gather straight from (B,C,N)
      for (int u = 0; u < 16; ++u) {
        int c = q * 16 + u;
        h[(3 + c) * HS + ss] = fsrc[((size_t)b * NC + c) * NN + j];
      }
    }
    if (q == 0) {  // relative xyz (exact fp32 subtraction, matches reference)
      const float* pr = xyz + ((size_t)b * NN + j) * 3;
      h[0 * HS + ss] = pr[0] - sc[0];
      h[1 * HS + ss] = pr[1] - sc[1];
      h[2 * HS + ss] = pr[2] - sc[2];
    }
  }
  __syncthreads();
  {  // layer1: lane o (64 outs), 4 groups x 8 samples
    const int o = tid & 63, sg = tid >> 6;
    float acc[8];
    const float bb = b1[o];
#pragma unroll
    for (int i = 0; i < 8; ++i) acc[i] = bb;
    const float4* hb = (const float4*)&h[sg * 8];
    for (int k = 0; k < CIN; ++k) {
      float w = w1t[k * NH1 + o];
      float4 a = hb[k * (HS / 4) + 0];
      float4 c = hb[k * (HS / 4) + 1];
      acc[0] = fmaf(w, a.x, acc[0]); acc[1] = fmaf(w, a.y, acc[1]);
      acc[2] = fmaf(w, a.z, acc[2]); acc[3] = fmaf(w, a.w, acc[3]);
      acc[4] = fmaf(w, c.x, acc[4]); acc[5] = fmaf(w, c.y, acc[5]);
      acc[6] = fmaf(w, c.z, acc[6]); acc[7] = fmaf(w, c.w, acc[7]);
    }
#pragma unroll
    for (int i = 0; i < 8; ++i) h1[o * HS + sg * 8 + i] = fmaxf(acc[i], 0.0f);
  }
  __syncthreads();
  {  // layer2: lane o (128 outs), 2 groups x 16 samples; fused partial maxpool
    const int o = tid & 127, sg = tid >> 7;
    float acc[16];
    const float bb = b2[o];
#pragma unroll
    for (int i = 0; i < 16; ++i) acc[i] = bb;
    const float4* hb = (const float4*)&h1[sg * 16];
    for (int k = 0; k < NH1; ++k) {
      float w = w2t[k * NH2 + o];
#pragma unroll
      for (int u = 0; u < 4; ++u) {
        float4 a = hb[k * (HS / 4) + u];
        acc[u * 4 + 0] = fmaf(w, a.x, acc[u * 4 + 0]);
        acc[u * 4 + 1] = fmaf(w, a.y, acc[u * 4 + 1]);
        acc[u * 4 + 2] = fmaf(w, a.z, acc[u * 4 + 2]);
        acc[u * 4 + 3] = fmaf(w, a.w, acc[u * 4 + 3]);
      }
    }
    float pm = acc[0];
#pragma unroll
    for (int i = 1; i < 16; ++i) pm = fmaxf(pm, acc[i]);
    pl[sg * 128 + o] = pm;
  }
  __syncthreads();
  if (tid < NH2) pooled[tid] = fmaxf(fmaxf(pl[tid], pl[128 + tid]), 0.0f);
  __syncthreads();
  if (tid < NOUTC) {  // final linear, output layout (B, OUT, NPTS)
    float acc = bsa[tid];
    for (int k = 0; k < NH2; ++k) acc = fmaf(pooled[k], wsat[k * NOUTC + tid], acc);
    out1[((size_t)b * NOUTC + tid) * NPTS + s] = acc;
  }
}

extern "C" void kernel_launch(void* const* d_in, const int* in_sizes, int n_in,
                              void* d_out, int out_size, void* d_ws, size_t ws_size,
                              hipStream_t stream) {
  const float* xyz = (const float*)d_in[0];
  const float* feat = (const float*)d_in[1];
  const float* W1 = (const float*)d_in[2];
  const float* b1 = (const float*)d_in[3];
  const float* W2 = (const float*)d_in[4];
  const float* b2 = (const float*)d_in[5];
  const float* Wsa = (const float*)d_in[6];
  const float* bsa = (const float*)d_in[7];
  float* out = (float*)d_out;
  float* newxyz = out;                       // (B, NPTS, 3)
  float* out1 = out + (size_t)NB * NPTS * 3; // (B, OUT, NPTS)

  const size_t featT_f = (size_t)NB * NN * NC;
  const size_t small_f = (size_t)CIN * NH1 + NH1 * NH2 + NH2 * NOUTC +
                         (size_t)NB * NPTS * NSAMP;
  float* ws = (float*)d_ws;
  bool useT = ws_size >= (featT_f + small_f) * 4;
  float* featT = ws;
  float* w1t = ws + (useT ? featT_f : 0);
  float* w2t = w1t + CIN * NH1;
  float* wsat = w2t + NH1 * NH2;
  int* bidx = (int*)(wsat + NH2 * NOUTC);

  tw_kernel<<<64, 256, 0, stream>>>(W1, W2, Wsa, w1t, w2t, wsat);
  if (useT)
    tfeat_kernel<<<dim3(NN / 32, NC / 32, NB), dim3(32, 8), 0, stream>>>(feat, featT);
  fps_kernel<<<NB, 1024, 0, stream>>>(xyz, newxyz);
  ballq_kernel<<<NB * NPTS / 4, 256, 0, stream>>>(xyz, newxyz, bidx);
  mlp_kernel<<<NB * NPTS, 256, 0, stream>>>(xyz, useT ? featT : feat, newxyz, bidx,
                                            w1t, b1, w2t, b2, wsat, bsa, out1,
                                            (int)useT);
}

// Round 2
// 3739.574 us; speedup vs baseline: 1.0568x; 1.0568x over previous
//
#include <hip/hip_runtime.h>
#include <cstdint>
#include <cstddef>

#define NB 4
#define NN 8192
#define NPTS 2048
#define NSAMP 32
#define NC 128
#define CIN 131      // 3 + NC
#define NH1 64
#define NH2 128
#define NOUTC 128

typedef float v2f __attribute__((ext_vector_type(2)));

// Exact (numpy-order, contraction-free) squared distance:
// ((dx*dx + dy*dy) + dz*dz), round-to-nearest each op, no FMA.
__device__ __forceinline__ float d2_exact(float ax, float ay, float az,
                                          float bx, float by, float bz) {
  float dx = ax - bx, dy = ay - by, dz = az - bz;
  return __fadd_rn(__fadd_rn(__fmul_rn(dx, dx), __fmul_rn(dy, dy)),
                   __fmul_rn(dz, dz));
}

// ---- DPP cross-lane (VALU, no LDS) --------------------------------------
#if __has_builtin(__builtin_amdgcn_mov_dpp)
template <int CTRL>
__device__ __forceinline__ float dppf(float v) {
  return __int_as_float(
      __builtin_amdgcn_mov_dpp(__float_as_int(v), CTRL, 0xF, 0xF, true));
}
template <int CTRL>
__device__ __forceinline__ int dppi(int v) {
  return __builtin_amdgcn_mov_dpp(v, CTRL, 0xF, 0xF, true);
}
#else
template <int CTRL>
__device__ __forceinline__ float dppf(float v) {
  const int m = (CTRL == 0xB1) ? 1 : (CTRL == 0x4E) ? 2 : (CTRL == 0x141) ? 7 : 15;
  return __shfl_xor(v, m);
}
template <int CTRL>
__device__ __forceinline__ int dppi(int v) {
  const int m = (CTRL == 0xB1) ? 1 : (CTRL == 0x4E) ? 2 : (CTRL == 0x141) ? 7 : 15;
  return __shfl_xor(v, m);
}
#endif

// argmax combine: larger value wins; on equal value, smaller index wins
__device__ __forceinline__ void red_pair(float& bv, int& bi, float ov, int oi) {
  bool t = (ov > bv) || (ov == bv && oi < bi);
  bv = t ? ov : bv;
  bi = t ? oi : bi;
}

// ---------------------------------------------------------------------------
// FPS: one 1024-thread block per batch; 8 points per thread in packed regs.
// One barrier per step; DPP butterfly argmax; coords carried in registers.
// Bit-exact vs reference: dist=min(dist,d2) then argmax(dist), first-index ties.
// ---------------------------------------------------------------------------
__global__ __launch_bounds__(1024, 1) void fps_kernel(
    const float* __restrict__ xyz, float* __restrict__ newxyz) {
#pragma clang fp contract(off)
  const int b = blockIdx.x;
  const int tid = threadIdx.x;
  const int lane = tid & 63;
  const int wid = tid >> 6;
  const float* xb = xyz + (size_t)b * NN * 3;

  v2f x2[4], y2[4], z2[4], dd[4];
#pragma unroll
  for (int p = 0; p < 4; ++p) {
    int j0 = tid + ((2 * p) << 10);
    int j1 = tid + ((2 * p + 1) << 10);
    x2[p].x = xb[j0 * 3 + 0]; x2[p].y = xb[j1 * 3 + 0];
    y2[p].x = xb[j0 * 3 + 1]; y2[p].y = xb[j1 * 3 + 1];
    z2[p].x = xb[j0 * 3 + 2]; z2[p].y = xb[j1 * 3 + 2];
    dd[p].x = 1e10f; dd[p].y = 1e10f;
  }

  __shared__ float vbuf[2][16];
  __shared__ int ibuf[2][16];
  __shared__ float cbuf[2][16][3];

  // initial center = point 0 (read by all threads; broadcast load)
  float cx = xb[0], cy = xb[1], cz = xb[2];
  if (tid == 0) {
    newxyz[(size_t)b * NPTS * 3 + 0] = cx;
    newxyz[(size_t)b * NPTS * 3 + 1] = cy;
    newxyz[(size_t)b * NPTS * 3 + 2] = cz;
  }

  for (int t = 1; t < NPTS; ++t) {
    const int par = t & 1;
    v2f pxv = {cx, cx}, pyv = {cy, cy}, pzv = {cz, cz};
    float bv = -1.0f;
    int bi = 0;
    float bwx = 0.f, bwy = 0.f, bwz = 0.f;
#pragma unroll
    for (int p = 0; p < 4; ++p) {
      v2f dx = x2[p] - pxv;
      v2f dy = y2[p] - pyv;
      v2f dz = z2[p] - pzv;
      v2f s = dx * dx + dy * dy + dz * dz;  // contract(off): each op RN-rounded
      v2f nd;
      nd.x = fminf(dd[p].x, s.x);
      nd.y = fminf(dd[p].y, s.y);
      dd[p] = nd;
      {
        bool c = nd.x > bv;
        bv = c ? nd.x : bv; bi = c ? (tid + ((2 * p) << 10)) : bi;
        bwx = c ? x2[p].x : bwx; bwy = c ? y2[p].x : bwy; bwz = c ? z2[p].x : bwz;
      }
      {
        bool c = nd.y > bv;
        bv = c ? nd.y : bv; bi = c ? (tid + ((2 * p + 1) << 10)) : bi;
        bwx = c ? x2[p].y : bwx; bwy = c ? y2[p].y : bwy; bwz = c ? z2[p].y : bwz;
      }
    }
    // wave argmax: 4 DPP levels (xor1,2,7,15) + 2 shfl levels (xor16,32)
    red_pair(bv, bi, dppf<0xB1>(bv), dppi<0xB1>(bi));
    red_pair(bv, bi, dppf<0x4E>(bv), dppi<0x4E>(bi));
    red_pair(bv, bi, dppf<0x141>(bv), dppi<0x141>(bi));
    red_pair(bv, bi, dppf<0x140>(bv), dppi<0x140>(bi));
    red_pair(bv, bi, __shfl_xor(bv, 16), __shfl_xor(bi, 16));
    red_pair(bv, bi, __shfl_xor(bv, 32), __shfl_xor(bi, 32));
    // wave-winner thread publishes (val,idx,coords) for this wave
    if (tid == (bi & 1023)) {
      vbuf[par][wid] = bv;
      ibuf[par][wid] = bi;
      cbuf[par][wid][0] = bwx; cbuf[par][wid][1] = bwy; cbuf[par][wid][2] = bwz;
    }
    __syncthreads();
    // cross-wave: 16 partials, 4 DPP levels within each 16-lane row
    float v2w = vbuf[par][lane & 15];
    int i2w = ibuf[par][lane & 15];
    red_pair(v2w, i2w, dppf<0xB1>(v2w), dppi<0xB1>(i2w));
    red_pair(v2w, i2w, dppf<0x4E>(v2w), dppi<0x4E>(i2w));
    red_pair(v2w, i2w, dppf<0x141>(v2w), dppi<0x141>(i2w));
    red_pair(v2w, i2w, dppf<0x140>(v2w), dppi<0x140>(i2w));
    const int slot = (i2w & 1023) >> 6;
    cx = cbuf[par][slot][0]; cy = cbuf[par][slot][1]; cz = cbuf[par][slot][2];
    if (tid == (i2w & 1023)) {
      size_t o = ((size_t)b * NPTS + t) * 3;
      newxyz[o + 0] = cx; newxyz[o + 1] = cy; newxyz[o + 2] = cz;
    }
    // no second barrier: next step writes the other parity's slots; the
    // step-(t+1) barrier orders reuse of this parity at step t+2.
  }
}

// ---------------------------------------------------------------------------
// Ball query: one wave per center; ballot scan in index order -> first 32 hits.
// 0.04f is bitwise the f32 rounding of python 0.2*0.2.
// ---------------------------------------------------------------------------
__global__ __launch_bounds__(256) void ballq_kernel(
    const float* __restrict__ xyz, const float* __restrict__ newxyz,
    int* __restrict__ bidx) {
  const int cid = blockIdx.x * 4 + (threadIdx.x >> 6);
  const int lane = threadIdx.x & 63;
  const int b = cid >> 11;
  const float* xb = xyz + (size_t)b * NN * 3;
  const float cx = newxyz[(size_t)cid * 3 + 0];
  const float cy = newxyz[(size_t)cid * 3 + 1];
  const float cz = newxyz[(size_t)cid * 3 + 2];
  int* ob = bidx + (size_t)cid * NSAMP;
  int total = 0;
  int first = -1;
  for (int c0 = 0; c0 < NN; c0 += 64) {
    int j = c0 + lane;
    float xx = xb[j * 3 + 0], yy = xb[j * 3 + 1], zz = xb[j * 3 + 2];
    float d2 = d2_exact(cx, cy, cz, xx, yy, zz);
    bool in = d2 <= 0.04f;
    unsigned long long m = __ballot(in);
    if (first < 0 && m) first = c0 + __builtin_ctzll(m);
    int pos = total + __popcll(m & ((1ull << lane) - 1ull));
    if (in && pos < NSAMP) ob[pos] = j;
    total += __popcll(m);
    if (total >= NSAMP) break;
  }
  if (total < NSAMP && lane < NSAMP - total) ob[total + lane] = first;
}

// ---------------------------------------------------------------------------
// Weight transposes (tiny) so MLP weight reads are lane-coalesced [k][o].
// ---------------------------------------------------------------------------
__global__ void tw_kernel(const float* __restrict__ W1, const float* __restrict__ W2,
                          const float* __restrict__ Wsa, float* __restrict__ w1t,
                          float* __restrict__ w2t, float* __restrict__ wsat) {
  int i = blockIdx.x * blockDim.x + threadIdx.x;
  if (i < CIN * NH1) w1t[i] = W1[(i % NH1) * CIN + (i / NH1)];
  if (i < NH1 * NH2) w2t[i] = W2[(i % NH2) * NH1 + (i / NH2)];
  if (i < NH2 * NOUTC) wsat[i] = Wsa[(i % NOUTC) * NH2 + (i / NOUTC)];
}

// Features (B,C,N) -> (B,N,C) so per-point gathers are contiguous 512B rows.
__global__ void tfeat_kernel(const float* __restrict__ feat, float* __restrict__ featT) {
  __shared__ float tile[32][33];
  const int b = blockIdx.z;
  const int n0 = blockIdx.x * 32, c0 = blockIdx.y * 32;
  const int tx = threadIdx.x, ty = threadIdx.y;
#pragma unroll
  for (int r = 0; r < 4; ++r)
    tile[ty + r * 8][tx] = feat[((size_t)b * NC + c0 + ty + r * 8) * NN + n0 + tx];
  __syncthreads();
#pragma unroll
  for (int r = 0; r < 4; ++r)
    featT[((size_t)b * NN + n0 + ty + r * 8) * NC + c0 + tx] = tile[tx][ty + r * 8];
}

// ---------------------------------------------------------------------------
// Fused gather + MLP(64,128) + maxpool + final linear, one block per center.
// LDS layouts [k][s] with stride 36 so operand reads are float4 broadcasts.
// ---------------------------------------------------------------------------
#define HS 36
__global__ __launch_bounds__(256) void mlp_kernel(
    const float* __restrict__ xyz, const float* __restrict__ fsrc,
    const float* __restrict__ newxyz, const int* __restrict__ bidx,
    const float* __restrict__ w1t, const float* __restrict__ b1,
    const float* __restrict__ w2t, const float* __restrict__ b2,
    const float* __restrict__ wsat, const float* __restrict__ bsa,
    float* __restrict__ out1, int useT) {
  __shared__ float h[CIN * HS];
  __shared__ float h1[NH1 * HS];
  __shared__ float pl[256];
  __shared__ float pooled[NH2];
  __shared__ int sidx[NSAMP];
  __shared__ float sc[3];
  const int cid = blockIdx.x;
  const int b = cid >> 11;
  const int s = cid & 2047;
  const int tid = threadIdx.x;
  if (tid < NSAMP) sidx[tid] = bidx[(size_t)cid * NSAMP + tid];
  if (tid < 3) sc[tid] = newxyz[(size_t)cid * 3 + tid];
  __syncthreads();
  {  // gather: 8 threads per sample read its 128-float feature row
    const int ss = tid >> 3, q = tid & 7;
    const int j = sidx[ss];
    if (useT) {
      const float4* fr = (const float4*)(fsrc + ((size_t)b * NN + j) * NC + q * 16);
#pragma unroll
      for (int u = 0; u < 4; ++u) {
        float4 v = fr[u];
        int c = 3 + q * 16 + u * 4;
        h[(c + 0) * HS + ss] = v.x;
        h[(c + 1) * HS + ss] = v.y;
        h[(c + 2) * HS + ss] = v.z;
        h[(c + 3) * HS + ss] = v.w;
      }
    } else {  // ws too small: strided gather straight from (B,C,N)
      for (int u = 0; u < 16; ++u) {
        int c = q * 16 + u;
        h[(3 + c) * HS + ss] = fsrc[((size_t)b * NC + c) * NN + j];
      }
    }
    if (q == 0) {  // relative xyz (exact fp32 subtraction, matches reference)
      const float* pr = xyz + ((size_t)b * NN + j) * 3;
      h[0 * HS + ss] = pr[0] - sc[0];
      h[1 * HS + ss] = pr[1] - sc[1];
      h[2 * HS + ss] = pr[2] - sc[2];
    }
  }
  __syncthreads();
  {  // layer1: lane o (64 outs), 4 groups x 8 samples
    const int o = tid & 63, sg = tid >> 6;
    float acc[8];
    const float bb = b1[o];
#pragma unroll
    for (int i = 0; i < 8; ++i) acc[i] = bb;
    const float4* hb = (const float4*)&h[sg * 8];
    for (int k = 0; k < CIN; ++k) {
      float w = w1t[k * NH1 + o];
      float4 a = hb[k * (HS / 4) + 0];
      float4 c = hb[k * (HS / 4) + 1];
      acc[0] = fmaf(w, a.x, acc[0]); acc[1] = fmaf(w, a.y, acc[1]);
      acc[2] = fmaf(w, a.z, acc[2]); acc[3] = fmaf(w, a.w, acc[3]);
      acc[4] = fmaf(w, c.x, acc[4]); acc[5] = fmaf(w, c.y, acc[5]);
      acc[6] = fmaf(w, c.z, acc[6]); acc[7] = fmaf(w, c.w, acc[7]);
    }
#pragma unroll
    for (int i = 0; i < 8; ++i) h1[o * HS + sg * 8 + i] = fmaxf(acc[i], 0.0f);
  }
  __syncthreads();
  {  // layer2: lane o (128 outs), 2 groups x 16 samples; fused partial maxpool
    const int o = tid & 127, sg = tid >> 7;
    float acc[16];
    const float bb = b2[o];
#pragma unroll
    for (int i = 0; i < 16; ++i) acc[i] = bb;
    const float4* hb = (const float4*)&h1[sg * 16];
    for (int k = 0; k < NH1; ++k) {
      float w = w2t[k * NH2 + o];
#pragma unroll
      for (int u = 0; u < 4; ++u) {
        float4 a = hb[k * (HS / 4) + u];
        acc[u * 4 + 0] = fmaf(w, a.x, acc[u * 4 + 0]);
        acc[u * 4 + 1] = fmaf(w, a.y, acc[u * 4 + 1]);
        acc[u * 4 + 2] = fmaf(w, a.z, acc[u * 4 + 2]);
        acc[u * 4 + 3] = fmaf(w, a.w, acc[u * 4 + 3]);
      }
    }
    float pm = acc[0];
#pragma unroll
    for (int i = 1; i < 16; ++i) pm = fmaxf(pm, acc[i]);
    pl[sg * 128 + o] = pm;
  }
  __syncthreads();
  if (tid < NH2) pooled[tid] = fmaxf(fmaxf(pl[tid], pl[128 + tid]), 0.0f);
  __syncthreads();
  if (tid < NOUTC) {  // final linear, output layout (B, OUT, NPTS)
    float acc = bsa[tid];
    for (int k = 0; k < NH2; ++k) acc = fmaf(pooled[k], wsat[k * NOUTC + tid], acc);
    out1[((size_t)b * NOUTC + tid) * NPTS + s] = acc;
  }
}

extern "C" void kernel_launch(void* const* d_in, const int* in_sizes, int n_in,
                              void* d_out, int out_size, void* d_ws, size_t ws_size,
                              hipStream_t stream) {
  const float* xyz = (const float*)d_in[0];
  const float* feat = (const float*)d_in[1];
  const float* W1 = (const float*)d_in[2];
  const float* b1 = (const float*)d_in[3];
  const float* W2 = (const float*)d_in[4];
  const float* b2 = (const float*)d_in[5];
  const float* Wsa = (const float*)d_in[6];
  const float* bsa = (const float*)d_in[7];
  float* out = (float*)d_out;
  float* newxyz = out;                       // (B, NPTS, 3)
  float* out1 = out + (size_t)NB * NPTS * 3; // (B, OUT, NPTS)

  const size_t featT_f = (size_t)NB * NN * NC;
  const size_t small_f = (size_t)CIN * NH1 + NH1 * NH2 + NH2 * NOUTC +
                         (size_t)NB * NPTS * NSAMP;
  float* ws = (float*)d_ws;
  bool useT = ws_size >= (featT_f + small_f) * 4;
  float* featT = ws;
  float* w1t = ws + (useT ? featT_f : 0);
  float* w2t = w1t + CIN * NH1;
  float* wsat = w2t + NH1 * NH2;
  int* bidx = (int*)(wsat + NH2 * NOUTC);

  tw_kernel<<<64, 256, 0, stream>>>(W1, W2, Wsa, w1t, w2t, wsat);
  if (useT)
    tfeat_kernel<<<dim3(NN / 32, NC / 32, NB), dim3(32, 8), 0, stream>>>(feat, featT);
  fps_kernel<<<NB, 1024, 0, stream>>>(xyz, newxyz);
  ballq_kernel<<<NB * NPTS / 4, 256, 0, stream>>>(xyz, newxyz, bidx);
  mlp_kernel<<<NB * NPTS, 256, 0, stream>>>(xyz, useT ? featT : feat, newxyz, bidx,
                                            w1t, b1, w2t, b2, wsat, bsa, out1,
                                            (int)useT);
}